// Round 1
// baseline (1644.252 us; speedup 1.0000x reference)
//
#include <hip/hip_runtime.h>
#include <math.h>

// ---- problem constants ----
#define NB      8
#define C_IN    3
#define HIMG    512
#define WIMG    512
#define C1      64      // conv1 out channels
#define HMID    256     // after pool1
#define WMID    256
#define C2      128     // conv2 out channels (C_FEAT)
#define HFT     128     // after pool2
#define WFT     128
#define NROIS   256
#define ROI_FT  32
#define SPP_DIM 2688    // 128*(1+4+16)
#define FC1_OUT 256
#define NCLS    1000

// ---------------------------------------------------------------------------
// Kernel A: conv1 (3x3, pad1) + bias + relu + 2x2 maxpool, fused.
// Block: 256 threads = 16x16 pooled tile. blockIdx: (tile 16x16, ocg of 16, b)
// ---------------------------------------------------------------------------
__global__ __launch_bounds__(256)
void k_conv1_pool(const float* __restrict__ x, const float* __restrict__ w1,
                  const float* __restrict__ b1, float* __restrict__ mid)
{
    __shared__ float sm_in[3 * 34 * 35];   // [c][r][col], row stride 35
    __shared__ float sm_w[16 * 27];
    __shared__ float sm_b[16];

    const int tid = threadIdx.x;
    const int tile = blockIdx.x;           // 0..255 (16x16 tiles)
    const int ocg  = blockIdx.y;           // 0..3
    const int b    = blockIdx.z;

    const int ty0 = (tile >> 4) * 16;      // pooled-tile origin
    const int tx0 = (tile & 15) * 16;
    const int iy0 = 2 * ty0 - 1;           // input origin (with halo)
    const int ix0 = 2 * tx0 - 1;

    // stage input halo tile: 3 ch x 34 x 34
    for (int idx = tid; idx < 3 * 34 * 34; idx += 256) {
        int c   = idx / 1156;
        int rem = idx - c * 1156;
        int r   = rem / 34;
        int col = rem - r * 34;
        int gy = iy0 + r, gx = ix0 + col;
        float v = 0.f;
        if (gy >= 0 && gy < HIMG && gx >= 0 && gx < WIMG)
            v = x[((b * C_IN + c) * HIMG + gy) * WIMG + gx];
        sm_in[c * (34 * 35) + r * 35 + col] = v;
    }
    // stage weights for this oc group
    for (int idx = tid; idx < 16 * 27; idx += 256)
        sm_w[idx] = w1[(ocg * 16) * 27 + idx];
    if (tid < 16) sm_b[tid] = b1[ocg * 16 + tid];
    __syncthreads();

    const int ly = tid >> 4, lx = tid & 15;
    const int lr0 = 2 * ly, lc0 = 2 * lx;

    // load 4x4 patch per channel into regs
    float p[3][4][4];
    #pragma unroll
    for (int c = 0; c < 3; ++c) {
        const float* bp = &sm_in[c * (34 * 35) + lr0 * 35 + lc0];
        #pragma unroll
        for (int r = 0; r < 4; ++r) {
            p[c][r][0] = bp[r * 35 + 0];
            p[c][r][1] = bp[r * 35 + 1];
            p[c][r][2] = bp[r * 35 + 2];
            p[c][r][3] = bp[r * 35 + 3];
        }
    }

    const int py = ty0 + ly, px = tx0 + lx;
    for (int o = 0; o < 16; ++o) {
        const float* wp = &sm_w[o * 27];
        float s00 = 0.f, s01 = 0.f, s10 = 0.f, s11 = 0.f;
        #pragma unroll
        for (int c = 0; c < 3; ++c) {
            #pragma unroll
            for (int dy = 0; dy < 3; ++dy) {
                #pragma unroll
                for (int dx = 0; dx < 3; ++dx) {
                    float w = wp[c * 9 + dy * 3 + dx];
                    s00 = fmaf(p[c][dy    ][dx    ], w, s00);
                    s01 = fmaf(p[c][dy    ][dx + 1], w, s01);
                    s10 = fmaf(p[c][dy + 1][dx    ], w, s10);
                    s11 = fmaf(p[c][dy + 1][dx + 1], w, s11);
                }
            }
        }
        float mx = fmaxf(fmaxf(s00, s01), fmaxf(s10, s11));
        float v = fmaxf(mx + sm_b[o], 0.f);
        int oc = ocg * 16 + o;
        mid[((b * C1 + oc) * HMID + py) * WMID + px] = v;
    }
}

// ---------------------------------------------------------------------------
// Kernel B: conv2 (64->128, 3x3, pad1) + bias + relu + 2x2 maxpool, fused.
// Block: 256 threads = 16x16 pooled tile, 16 oc per block, ci chunks of 8.
// ---------------------------------------------------------------------------
__global__ __launch_bounds__(256)
void k_conv2_pool(const float* __restrict__ mid, const float* __restrict__ w2,
                  const float* __restrict__ b2, float* __restrict__ feat)
{
    __shared__ float sm_in[8 * 34 * 36];    // [c][r][col], row stride 36
    __shared__ float sm_w[8 * 16 * 12];     // [c][o][12] (9 used, padded)

    const int tid = threadIdx.x;
    const int tile = blockIdx.x;            // 0..63 (8x8 tiles)
    const int ocg  = blockIdx.y;            // 0..7
    const int b    = blockIdx.z;

    const int ty0 = (tile >> 3) * 16;
    const int tx0 = (tile & 7) * 16;
    const int iy0 = 2 * ty0 - 1;
    const int ix0 = 2 * tx0 - 1;

    const int ly = tid >> 4, lx = tid & 15;
    const int lr0 = 2 * ly, lc0 = 2 * lx;

    float acc[16][4];
    #pragma unroll
    for (int o = 0; o < 16; ++o)
        #pragma unroll
        for (int q = 0; q < 4; ++q) acc[o][q] = 0.f;

    for (int cig = 0; cig < 8; ++cig) {
        __syncthreads();   // protect previous iteration's reads
        // stage 8-channel input halo tile
        for (int idx = tid; idx < 8 * 34 * 34; idx += 256) {
            int c   = idx / 1156;
            int rem = idx - c * 1156;
            int r   = rem / 34;
            int col = rem - r * 34;
            int gy = iy0 + r, gx = ix0 + col;
            float v = 0.f;
            if (gy >= 0 && gy < HMID && gx >= 0 && gx < WMID)
                v = mid[((b * C1 + cig * 8 + c) * HMID + gy) * WMID + gx];
            sm_in[c * (34 * 36) + r * 36 + col] = v;
        }
        // stage weights [c][o][0..8]
        for (int idx = tid; idx < 8 * 16 * 9; idx += 256) {
            int o   = idx / 72;
            int rem = idx - o * 72;
            int c   = rem / 9;
            int k   = rem - c * 9;
            sm_w[(c * 16 + o) * 12 + k] = w2[((ocg * 16 + o) * C1 + cig * 8 + c) * 9 + k];
        }
        __syncthreads();

        for (int c = 0; c < 8; ++c) {
            float p[4][4];
            const float* bp = &sm_in[c * (34 * 36) + lr0 * 36 + lc0];
            #pragma unroll
            for (int r = 0; r < 4; ++r) {
                float2 a0 = *(const float2*)(bp + r * 36);
                float2 a1 = *(const float2*)(bp + r * 36 + 2);
                p[r][0] = a0.x; p[r][1] = a0.y; p[r][2] = a1.x; p[r][3] = a1.y;
            }
            for (int o = 0; o < 16; ++o) {
                const float* wp = &sm_w[(c * 16 + o) * 12];
                float4 wa = *(const float4*)(wp);       // w00 w01 w02 w10
                float4 wb = *(const float4*)(wp + 4);   // w11 w12 w20 w21
                float w8  = wp[8];                      // w22
                #pragma unroll
                for (int qy = 0; qy < 2; ++qy) {
                    #pragma unroll
                    for (int qx = 0; qx < 2; ++qx) {
                        float s = p[qy][qx]     * wa.x + p[qy][qx + 1]     * wa.y
                                + p[qy][qx + 2] * wa.z + p[qy + 1][qx]     * wa.w
                                + p[qy + 1][qx + 1] * wb.x + p[qy + 1][qx + 2] * wb.y
                                + p[qy + 2][qx]     * wb.z + p[qy + 2][qx + 1] * wb.w
                                + p[qy + 2][qx + 2] * w8;
                        acc[o][qy * 2 + qx] += s;
                    }
                }
            }
        }
    }

    const int py = ty0 + ly, px = tx0 + lx;
    for (int o = 0; o < 16; ++o) {
        int oc = ocg * 16 + o;
        float mx = fmaxf(fmaxf(acc[o][0], acc[o][1]), fmaxf(acc[o][2], acc[o][3]));
        float v = fmaxf(mx + b2[oc], 0.f);
        feat[((b * C2 + oc) * HFT + py) * WFT + px] = v;
    }
}

// ---------------------------------------------------------------------------
// Kernel C: ROI crop + SPP (max over 1x1 / 2x2 / 4x4 grids). Block per ROI.
// ---------------------------------------------------------------------------
__global__ __launch_bounds__(256)
void k_roi_spp(const float* __restrict__ feat, const int* __restrict__ rois,
               float* __restrict__ spp)
{
    __shared__ float sm_blk[128 * 17];   // [c][blk], stride 17 (conflict-free)

    const int tid = threadIdx.x;
    const int roi = blockIdx.x;

    const int bi = rois[roi * 5 + 0];
    int xm = (int)roundf((float)rois[roi * 5 + 1] * 0.25f);
    int ym = (int)roundf((float)rois[roi * 5 + 2] * 0.25f);
    xm = min(max(xm, 0), WFT - ROI_FT);
    ym = min(max(ym, 0), HFT - ROI_FT);

    // phase 1: 8x8 block maxes — 2048 units (128 ch x 16 blocks)
    #pragma unroll
    for (int it = 0; it < 8; ++it) {
        int u   = tid + it * 256;
        int c   = u >> 4;
        int blk = u & 15;
        int by  = blk >> 2, bx = blk & 3;
        const float* base = &feat[((bi * C2 + c) * HFT + ym + by * 8) * WFT + xm + bx * 8];
        float m = -INFINITY;
        #pragma unroll
        for (int i = 0; i < 8; ++i)
            #pragma unroll
            for (int j = 0; j < 8; ++j)
                m = fmaxf(m, base[i * WFT + j]);
        sm_blk[c * 17 + blk] = m;
    }
    __syncthreads();

    // phase 2: derive p=4 (16), p=2 (4), p=1 (1) per channel
    if (tid < 128) {
        float v[16];
        #pragma unroll
        for (int k = 0; k < 16; ++k) v[k] = sm_blk[tid * 17 + k];
        float* o = spp + (size_t)roi * SPP_DIM;
        #pragma unroll
        for (int k = 0; k < 16; ++k) o[640 + tid * 16 + k] = v[k];
        float g = -INFINITY;
        #pragma unroll
        for (int qy = 0; qy < 2; ++qy) {
            #pragma unroll
            for (int qx = 0; qx < 2; ++qx) {
                float q = fmaxf(fmaxf(v[(2 * qy) * 4 + 2 * qx],     v[(2 * qy) * 4 + 2 * qx + 1]),
                                fmaxf(v[(2 * qy + 1) * 4 + 2 * qx], v[(2 * qy + 1) * 4 + 2 * qx + 1]));
                o[128 + tid * 4 + qy * 2 + qx] = q;
                g = fmaxf(g, q);
            }
        }
        o[tid] = g;
    }
}

// ---------------------------------------------------------------------------
// Kernel D: FC1 + relu. Block per row (256 outputs).
// ---------------------------------------------------------------------------
__global__ __launch_bounds__(256)
void k_fc1(const float* __restrict__ spp, const float* __restrict__ fc1_w,
           const float* __restrict__ fc1_b, float* __restrict__ h)
{
    __shared__ float srow[SPP_DIM];
    const int tid = threadIdx.x;
    const int row = blockIdx.x;
    for (int k = tid; k < SPP_DIM; k += 256) srow[k] = spp[(size_t)row * SPP_DIM + k];
    __syncthreads();

    float acc = fc1_b[tid];
    for (int k0 = 0; k0 < SPP_DIM; k0 += 4) {
        float4 s4 = *(const float4*)&srow[k0];
        acc = fmaf(s4.x, fc1_w[(k0 + 0) * FC1_OUT + tid], acc);
        acc = fmaf(s4.y, fc1_w[(k0 + 1) * FC1_OUT + tid], acc);
        acc = fmaf(s4.z, fc1_w[(k0 + 2) * FC1_OUT + tid], acc);
        acc = fmaf(s4.w, fc1_w[(k0 + 3) * FC1_OUT + tid], acc);
    }
    h[row * FC1_OUT + tid] = fmaxf(acc, 0.f);
}

// ---------------------------------------------------------------------------
// Kernel E: FC2. Block per row (1000 outputs, strided).
// ---------------------------------------------------------------------------
__global__ __launch_bounds__(256)
void k_fc2(const float* __restrict__ h, const float* __restrict__ fc2_w,
           const float* __restrict__ fc2_b, float* __restrict__ out)
{
    __shared__ float hrow[FC1_OUT];
    const int tid = threadIdx.x;
    const int row = blockIdx.x;
    hrow[tid] = h[row * FC1_OUT + tid];
    __syncthreads();

    for (int n = tid; n < NCLS; n += 256) {
        float acc = fc2_b[n];
        for (int k0 = 0; k0 < FC1_OUT; k0 += 4) {
            float4 h4 = *(const float4*)&hrow[k0];
            acc = fmaf(h4.x, fc2_w[(k0 + 0) * NCLS + n], acc);
            acc = fmaf(h4.y, fc2_w[(k0 + 1) * NCLS + n], acc);
            acc = fmaf(h4.z, fc2_w[(k0 + 2) * NCLS + n], acc);
            acc = fmaf(h4.w, fc2_w[(k0 + 3) * NCLS + n], acc);
        }
        out[row * NCLS + n] = acc;
    }
}

// ---------------------------------------------------------------------------
extern "C" void kernel_launch(void* const* d_in, const int* in_sizes, int n_in,
                              void* d_out, int out_size, void* d_ws, size_t ws_size,
                              hipStream_t stream)
{
    const float* x     = (const float*)d_in[0];
    const int*   rois  = (const int*)  d_in[1];
    const float* w1    = (const float*)d_in[2];
    const float* b1    = (const float*)d_in[3];
    const float* w2    = (const float*)d_in[4];
    const float* b2    = (const float*)d_in[5];
    const float* fc1_w = (const float*)d_in[6];
    const float* fc1_b = (const float*)d_in[7];
    const float* fc2_w = (const float*)d_in[8];
    const float* fc2_b = (const float*)d_in[9];
    float* out = (float*)d_out;

    // workspace layout (floats): mid | feat | spp | h  — ~204 MB total
    float* ws   = (float*)d_ws;
    float* mid  = ws;                                        // 8*64*256*256
    float* feat = mid  + (size_t)NB * C1 * HMID * WMID;      // 8*128*128*128
    float* spp  = feat + (size_t)NB * C2 * HFT * WFT;        // 256*2688
    float* h    = spp  + (size_t)NROIS * SPP_DIM;            // 256*256

    k_conv1_pool<<<dim3(256, 4, NB), 256, 0, stream>>>(x, w1, b1, mid);
    k_conv2_pool<<<dim3(64, 8, NB), 256, 0, stream>>>(mid, w2, b2, feat);
    k_roi_spp<<<dim3(NROIS), 256, 0, stream>>>(feat, rois, spp);
    k_fc1<<<dim3(NROIS), 256, 0, stream>>>(spp, fc1_w, fc1_b, h);
    k_fc2<<<dim3(NROIS), 256, 0, stream>>>(h, fc2_w, fc2_b, out);
}

// Round 2
// 417.099 us; speedup vs baseline: 3.9421x; 3.9421x over previous
//
#include <hip/hip_runtime.h>
#include <math.h>

// ---- problem constants ----
#define NB      8
#define C_IN    3
#define HIMG    512
#define WIMG    512
#define C1      64      // conv1 out channels
#define HMID    256     // after pool1
#define WMID    256
#define C2      128     // conv2 out channels (C_FEAT)
#define HFT     128     // after pool2
#define WFT     128
#define NROIS   256
#define ROI_FT  32
#define SPP_DIM 2688    // 128*(1+4+16)
#define FC1_OUT 256
#define NCLS    1000

typedef unsigned short ushort;
typedef __attribute__((ext_vector_type(8))) short short8;
typedef __attribute__((ext_vector_type(4))) float f32x4;

static __device__ __forceinline__ ushort f2bf(float f) {
    unsigned u = __builtin_bit_cast(unsigned, f);
    unsigned r = (u + 0x7fffu + ((u >> 16) & 1u)) >> 16;   // RNE
    return (ushort)r;
}

// ---------------------------------------------------------------------------
// Kernel W: transpose w2 [oc][ci][3][3] fp32 -> Wt [tap][oc][ci] bf16
// ---------------------------------------------------------------------------
__global__ __launch_bounds__(256)
void k_w2t(const float* __restrict__ w2, ushort* __restrict__ Wt)
{
    int i = blockIdx.x * 256 + threadIdx.x;      // 9*128*64 = 73728
    if (i >= 9 * 128 * 64) return;
    int tap = i >> 13;
    int rem = i & 8191;
    int oc  = rem >> 6;
    int ci  = rem & 63;
    Wt[i] = f2bf(w2[(oc * 64 + ci) * 9 + tap]);
}

// ---------------------------------------------------------------------------
// Kernel A: conv1 (3x3, pad1) + bias + relu + 2x2 maxpool -> mid bf16 NHWC
// ---------------------------------------------------------------------------
__global__ __launch_bounds__(256)
void k_conv1_pool(const float* __restrict__ x, const float* __restrict__ w1,
                  const float* __restrict__ b1, ushort* __restrict__ mid)
{
    __shared__ float sm_in[3 * 34 * 35];   // [c][r][col], row stride 35
    __shared__ float sm_w[16 * 27];
    __shared__ float sm_b[16];

    const int tid = threadIdx.x;
    const int tile = blockIdx.x;           // 0..255
    const int ocg  = blockIdx.y;           // 0..3
    const int b    = blockIdx.z;

    const int ty0 = (tile >> 4) * 16;
    const int tx0 = (tile & 15) * 16;
    const int iy0 = 2 * ty0 - 1;
    const int ix0 = 2 * tx0 - 1;

    for (int idx = tid; idx < 3 * 34 * 34; idx += 256) {
        int c   = idx / 1156;
        int rem = idx - c * 1156;
        int r   = rem / 34;
        int col = rem - r * 34;
        int gy = iy0 + r, gx = ix0 + col;
        float v = 0.f;
        if (gy >= 0 && gy < HIMG && gx >= 0 && gx < WIMG)
            v = x[((b * C_IN + c) * HIMG + gy) * WIMG + gx];
        sm_in[c * (34 * 35) + r * 35 + col] = v;
    }
    for (int idx = tid; idx < 16 * 27; idx += 256)
        sm_w[idx] = w1[(ocg * 16) * 27 + idx];
    if (tid < 16) sm_b[tid] = b1[ocg * 16 + tid];
    __syncthreads();

    const int ly = tid >> 4, lx = tid & 15;
    const int lr0 = 2 * ly, lc0 = 2 * lx;

    float p[3][4][4];
    #pragma unroll
    for (int c = 0; c < 3; ++c) {
        const float* bp = &sm_in[c * (34 * 35) + lr0 * 35 + lc0];
        #pragma unroll
        for (int r = 0; r < 4; ++r) {
            p[c][r][0] = bp[r * 35 + 0];
            p[c][r][1] = bp[r * 35 + 1];
            p[c][r][2] = bp[r * 35 + 2];
            p[c][r][3] = bp[r * 35 + 3];
        }
    }

    const int py = ty0 + ly, px = tx0 + lx;
    union { ushort u[8]; uint4 v; } pk0, pk1;
    #pragma unroll
    for (int o = 0; o < 16; ++o) {
        const float* wp = &sm_w[o * 27];
        float s00 = 0.f, s01 = 0.f, s10 = 0.f, s11 = 0.f;
        #pragma unroll
        for (int c = 0; c < 3; ++c) {
            #pragma unroll
            for (int dy = 0; dy < 3; ++dy) {
                #pragma unroll
                for (int dx = 0; dx < 3; ++dx) {
                    float w = wp[c * 9 + dy * 3 + dx];
                    s00 = fmaf(p[c][dy    ][dx    ], w, s00);
                    s01 = fmaf(p[c][dy    ][dx + 1], w, s01);
                    s10 = fmaf(p[c][dy + 1][dx    ], w, s10);
                    s11 = fmaf(p[c][dy + 1][dx + 1], w, s11);
                }
            }
        }
        float mx = fmaxf(fmaxf(s00, s01), fmaxf(s10, s11));
        float v = fmaxf(mx + sm_b[o], 0.f);
        ushort bv = f2bf(v);
        if (o < 8) pk0.u[o] = bv; else pk1.u[o - 8] = bv;
    }
    // mid NHWC bf16: [b][py][px][oc]
    ushort* mp = mid + ((size_t)((b * HMID + py) * WMID + px)) * C1 + ocg * 16;
    *(uint4*)mp = pk0.v;
    *((uint4*)mp + 1) = pk1.v;
}

// ---------------------------------------------------------------------------
// Kernel B: conv2 via bf16 MFMA implicit GEMM + bias + relu + 2x2 pool.
// Block: 512 thr (8 waves: 4 along x, 2 along oc). Conv tile 8y x 32x, 128 oc.
// LDS: halo 10 x 34 x 64ci bf16, [pos][ci] with XOR-swizzled 16B granules.
// K = 9 taps x 64 ci = 18 chunks of 32; zero barriers in K-loop.
// ---------------------------------------------------------------------------
__global__ __launch_bounds__(512, 4)
void k_conv2_mfma(const ushort* __restrict__ mid, const ushort* __restrict__ Wt,
                  const float* __restrict__ b2, float* __restrict__ feat)
{
    __shared__ uint4 sm_in[340 * 8];   // 10*34 positions x 8 granules (16B = 8 ci)

    const int tid = threadIdx.x;
    const int tx = blockIdx.x;         // 0..7   (32 conv cols each)
    const int ty = blockIdx.y;         // 0..31  (8 conv rows each)
    const int b  = blockIdx.z;

    const int cy0 = ty * 8, cx0 = tx * 32;

    // ---- stage halo tile (global NHWC bf16 -> LDS, swizzled) ----
    for (int t = tid; t < 340 * 8; t += 512) {
        int pos = t >> 3, g = t & 7;
        int hy = pos / 34, hx = pos - hy * 34;
        int gy = cy0 - 1 + hy, gx = cx0 - 1 + hx;
        uint4 v = make_uint4(0, 0, 0, 0);
        if ((unsigned)gy < (unsigned)HMID && (unsigned)gx < (unsigned)WMID)
            v = *(const uint4*)(mid + (((size_t)(b * HMID + gy) * WMID + gx) * C1 + g * 8));
        sm_in[pos * 8 + (g ^ (pos & 7))] = v;
    }
    __syncthreads();

    // ---- wave / lane decomposition ----
    const int l   = tid & 63;
    const int wid = tid >> 6;
    const int wm  = wid & 3;        // x-offset wm*8
    const int wn  = wid >> 2;       // oc-offset wn*64
    const int c16 = l & 15;
    const int hi  = l >> 4;
    const int ylane = (c16 >> 1) & 1;
    const int xlane = ((c16 >> 2) << 1) | (c16 & 1);
    const int pos00 = ylane * 34 + wm * 8 + xlane;   // halo coords of (y,x)+(dy=0,dx=0)
    const ushort* wbp = Wt + ((size_t)(wn * 64 + c16) * 64 + 8 * hi);

    f32x4 acc[4][4] = {};

    for (int tap = 0; tap < 9; ++tap) {
        int dy = tap / 3, dx = tap - dy * 3;
        int po = pos00 + dy * 34 + dx;
        const ushort* wt = wbp + tap * 8192;
        #pragma unroll
        for (int k0 = 0; k0 < 2; ++k0) {            // ci chunk k0*32
            short8 bf[4];
            #pragma unroll
            for (int fn = 0; fn < 4; ++fn)
                bf[fn] = *(const short8*)(wt + fn * 1024 + k0 * 32);
            #pragma unroll
            for (int fm = 0; fm < 4; ++fm) {
                int pos = po + fm * 68;             // fm*2 rows down
                int gi  = (hi + k0 * 4) ^ (pos & 7);
                short8 af = __builtin_bit_cast(short8, sm_in[pos * 8 + gi]);
                #pragma unroll
                for (int fn = 0; fn < 4; ++fn)
                    acc[fm][fn] = __builtin_amdgcn_mfma_f32_16x16x32_bf16(
                        af, bf[fn], acc[fm][fn], 0, 0, 0);
            }
        }
    }

    // ---- epilogue: each lane's 4 C/D regs = one 2x2 pool window ----
    // C/D: oc_frag = c16, m = hi*4 + r -> (y,x) = (fm*2 + (r>>1), hi*2 + (r&1))
    const int py0 = ty * 4;
    const int px  = tx * 16 + wm * 4 + hi;
    #pragma unroll
    for (int fn = 0; fn < 4; ++fn) {
        int oc = wn * 64 + fn * 16 + c16;
        float bb = b2[oc];
        #pragma unroll
        for (int fm = 0; fm < 4; ++fm) {
            f32x4 a4 = acc[fm][fn];
            float m = fmaxf(fmaxf(a4[0], a4[1]), fmaxf(a4[2], a4[3]));
            float v = fmaxf(m + bb, 0.f);
            feat[(((size_t)b * C2 + oc) * HFT + (py0 + fm)) * WFT + px] = v;
        }
    }
}

// ---------------------------------------------------------------------------
// Kernel C: ROI crop + SPP (max over 1x1 / 2x2 / 4x4 grids). Block per ROI.
// ---------------------------------------------------------------------------
__global__ __launch_bounds__(256)
void k_roi_spp(const float* __restrict__ feat, const int* __restrict__ rois,
               float* __restrict__ spp)
{
    __shared__ float sm_blk[128 * 17];

    const int tid = threadIdx.x;
    const int roi = blockIdx.x;

    const int bi = rois[roi * 5 + 0];
    int xm = (int)roundf((float)rois[roi * 5 + 1] * 0.25f);
    int ym = (int)roundf((float)rois[roi * 5 + 2] * 0.25f);
    xm = min(max(xm, 0), WFT - ROI_FT);
    ym = min(max(ym, 0), HFT - ROI_FT);

    #pragma unroll
    for (int it = 0; it < 8; ++it) {
        int u   = tid + it * 256;
        int c   = u >> 4;
        int blk = u & 15;
        int by  = blk >> 2, bx = blk & 3;
        const float* base = &feat[(((size_t)bi * C2 + c) * HFT + ym + by * 8) * WFT + xm + bx * 8];
        float m = -INFINITY;
        #pragma unroll
        for (int i = 0; i < 8; ++i)
            #pragma unroll
            for (int j = 0; j < 8; ++j)
                m = fmaxf(m, base[i * WFT + j]);
        sm_blk[c * 17 + blk] = m;
    }
    __syncthreads();

    if (tid < 128) {
        float v[16];
        #pragma unroll
        for (int k = 0; k < 16; ++k) v[k] = sm_blk[tid * 17 + k];
        float* o = spp + (size_t)roi * SPP_DIM;
        #pragma unroll
        for (int k = 0; k < 16; ++k) o[640 + tid * 16 + k] = v[k];
        float g = -INFINITY;
        #pragma unroll
        for (int qy = 0; qy < 2; ++qy) {
            #pragma unroll
            for (int qx = 0; qx < 2; ++qx) {
                float q = fmaxf(fmaxf(v[(2 * qy) * 4 + 2 * qx],     v[(2 * qy) * 4 + 2 * qx + 1]),
                                fmaxf(v[(2 * qy + 1) * 4 + 2 * qx], v[(2 * qy + 1) * 4 + 2 * qx + 1]));
                o[128 + tid * 4 + qy * 2 + qx] = q;
                g = fmaxf(g, q);
            }
        }
        o[tid] = g;
    }
}

// ---------------------------------------------------------------------------
// Kernel D: FC1 + relu. 16x16 output tile per block.
// ---------------------------------------------------------------------------
__global__ __launch_bounds__(256)
void k_fc1(const float* __restrict__ spp, const float* __restrict__ w,
           const float* __restrict__ bias, float* __restrict__ h)
{
    const int col = blockIdx.x * 16 + (threadIdx.x & 15);
    const int row = blockIdx.y * 16 + (threadIdx.x >> 4);
    const float* s = spp + (size_t)row * SPP_DIM;
    float acc = bias[col];
    for (int k = 0; k < SPP_DIM; k += 4) {
        float4 s4 = *(const float4*)(s + k);
        acc = fmaf(s4.x, w[(k + 0) * FC1_OUT + col], acc);
        acc = fmaf(s4.y, w[(k + 1) * FC1_OUT + col], acc);
        acc = fmaf(s4.z, w[(k + 2) * FC1_OUT + col], acc);
        acc = fmaf(s4.w, w[(k + 3) * FC1_OUT + col], acc);
    }
    h[row * FC1_OUT + col] = fmaxf(acc, 0.f);
}

// ---------------------------------------------------------------------------
// Kernel E: FC2. 16x16 output tile per block.
// ---------------------------------------------------------------------------
__global__ __launch_bounds__(256)
void k_fc2(const float* __restrict__ h, const float* __restrict__ w,
           const float* __restrict__ bias, float* __restrict__ out)
{
    const int col = blockIdx.x * 16 + (threadIdx.x & 15);
    const int row = blockIdx.y * 16 + (threadIdx.x >> 4);
    if (col >= NCLS) return;
    const float* hr = h + (size_t)row * FC1_OUT;
    float acc = bias[col];
    for (int k = 0; k < FC1_OUT; k += 4) {
        float4 h4 = *(const float4*)(hr + k);
        acc = fmaf(h4.x, w[(k + 0) * NCLS + col], acc);
        acc = fmaf(h4.y, w[(k + 1) * NCLS + col], acc);
        acc = fmaf(h4.z, w[(k + 2) * NCLS + col], acc);
        acc = fmaf(h4.w, w[(k + 3) * NCLS + col], acc);
    }
    out[row * NCLS + col] = acc;
}

// ---------------------------------------------------------------------------
extern "C" void kernel_launch(void* const* d_in, const int* in_sizes, int n_in,
                              void* d_out, int out_size, void* d_ws, size_t ws_size,
                              hipStream_t stream)
{
    const float* x     = (const float*)d_in[0];
    const int*   rois  = (const int*)  d_in[1];
    const float* w1    = (const float*)d_in[2];
    const float* b1    = (const float*)d_in[3];
    const float* w2    = (const float*)d_in[4];
    const float* b2    = (const float*)d_in[5];
    const float* fc1_w = (const float*)d_in[6];
    const float* fc1_b = (const float*)d_in[7];
    const float* fc2_w = (const float*)d_in[8];
    const float* fc2_b = (const float*)d_in[9];
    float* out = (float*)d_out;

    // workspace: mid bf16 | Wt bf16 | feat f32 | spp f32 | h f32  (~137 MB)
    ushort* midb = (ushort*)d_ws;
    ushort* Wt   = midb + (size_t)NB * HMID * WMID * C1;       // 33.55M elems
    float*  feat = (float*)(Wt + 9 * 128 * 64);                // 73728 elems
    float*  spp  = feat + (size_t)NB * C2 * HFT * WFT;         // 16.78M
    float*  h    = spp + (size_t)NROIS * SPP_DIM;

    k_w2t       <<<dim3(288),        256, 0, stream>>>(w2, Wt);
    k_conv1_pool<<<dim3(256, 4, NB), 256, 0, stream>>>(x, w1, b1, midb);
    k_conv2_mfma<<<dim3(8, 32, NB),  512, 0, stream>>>(midb, Wt, b2, feat);
    k_roi_spp   <<<dim3(NROIS),      256, 0, stream>>>(feat, rois, spp);
    k_fc1       <<<dim3(16, 16),     256, 0, stream>>>(spp, fc1_w, fc1_b, h);
    k_fc2       <<<dim3(63, 16),     256, 0, stream>>>(h, fc2_w, fc2_b, out);
}

// Round 3
// 376.984 us; speedup vs baseline: 4.3616x; 1.1064x over previous
//
#include <hip/hip_runtime.h>
#include <math.h>

// ---- problem constants ----
#define NB      8
#define C_IN    3
#define HIMG    512
#define WIMG    512
#define C1      64      // conv1 out channels
#define HMID    256     // after pool1
#define WMID    256
#define C2      128     // conv2 out channels (C_FEAT)
#define HFT     128     // after pool2
#define WFT     128
#define NROIS   256
#define ROI_FT  32
#define SPP_DIM 2688    // 128*(1+4+16)
#define FC1_OUT 256
#define NCLS    1000

typedef unsigned short ushort;
typedef __attribute__((ext_vector_type(8))) short short8;
typedef __attribute__((ext_vector_type(4))) float f32x4;

static __device__ __forceinline__ ushort f2bf(float f) {
    unsigned u = __builtin_bit_cast(unsigned, f);
    unsigned r = (u + 0x7fffu + ((u >> 16) & 1u)) >> 16;   // RNE
    return (ushort)r;
}

// ---------------------------------------------------------------------------
// Kernel W: transpose w2 [oc][ci][3][3] fp32 -> Wt [tap][oc][ci] bf16
// ---------------------------------------------------------------------------
__global__ __launch_bounds__(256)
void k_w2t(const float* __restrict__ w2, ushort* __restrict__ Wt)
{
    int i = blockIdx.x * 256 + threadIdx.x;      // 9*128*64 = 73728
    if (i >= 9 * 128 * 64) return;
    int tap = i >> 13;
    int rem = i & 8191;
    int oc  = rem >> 6;
    int ci  = rem & 63;
    Wt[i] = f2bf(w2[(oc * 64 + ci) * 9 + tap]);
}

// ---------------------------------------------------------------------------
// Kernel A: conv1 (3x3, pad1) + bias + relu + 2x2 maxpool -> mid bf16 NHWC.
// One block = 16x16 pooled tile, ALL 64 oc (input staged once, not 4x).
// Per-thread output = 64 contiguous bf16 = 128 B fully-coalesced store.
// ---------------------------------------------------------------------------
__global__ __launch_bounds__(256)
void k_conv1_pool(const float* __restrict__ x, const float* __restrict__ w1,
                  const float* __restrict__ b1, ushort* __restrict__ mid)
{
    __shared__ float sm_in[3 * 34 * 35];   // [c][r][col], row stride 35
    __shared__ float sm_w[64 * 28];        // row stride 28 (16B-aligned rows)
    __shared__ float sm_b[64];

    const int tid  = threadIdx.x;
    const int tile = blockIdx.x;           // 0..255
    const int b    = blockIdx.y;

    const int ty0 = (tile >> 4) * 16;
    const int tx0 = (tile & 15) * 16;
    const int iy0 = 2 * ty0 - 1;
    const int ix0 = 2 * tx0 - 1;

    for (int idx = tid; idx < 3 * 34 * 34; idx += 256) {
        int c   = idx / 1156;
        int rem = idx - c * 1156;
        int r   = rem / 34;
        int col = rem - r * 34;
        int gy = iy0 + r, gx = ix0 + col;
        float v = 0.f;
        if (gy >= 0 && gy < HIMG && gx >= 0 && gx < WIMG)
            v = x[((b * C_IN + c) * HIMG + gy) * WIMG + gx];
        sm_in[c * (34 * 35) + r * 35 + col] = v;
    }
    for (int idx = tid; idx < 64 * 27; idx += 256) {
        int o = idx / 27, k = idx - o * 27;
        sm_w[o * 28 + k] = w1[idx];
    }
    if (tid < 64) { sm_w[tid * 28 + 27] = 0.f; sm_b[tid] = b1[tid]; }
    __syncthreads();

    const int ly = tid >> 4, lx = tid & 15;
    const int lr0 = 2 * ly, lc0 = 2 * lx;

    float p[3][4][4];
    #pragma unroll
    for (int c = 0; c < 3; ++c) {
        const float* bp = &sm_in[c * (34 * 35) + lr0 * 35 + lc0];
        #pragma unroll
        for (int r = 0; r < 4; ++r) {
            p[c][r][0] = bp[r * 35 + 0];
            p[c][r][1] = bp[r * 35 + 1];
            p[c][r][2] = bp[r * 35 + 2];
            p[c][r][3] = bp[r * 35 + 3];
        }
    }

    const int py = ty0 + ly, px = tx0 + lx;
    union { ushort u[64]; uint4 v[8]; } pk;

    for (int o = 0; o < 64; ++o) {
        union { float4 q[7]; float w[28]; } wu;
        const float4* wq = (const float4*)&sm_w[o * 28];
        #pragma unroll
        for (int t = 0; t < 7; ++t) wu.q[t] = wq[t];

        float s00 = 0.f, s01 = 0.f, s10 = 0.f, s11 = 0.f;
        #pragma unroll
        for (int c = 0; c < 3; ++c) {
            #pragma unroll
            for (int dy = 0; dy < 3; ++dy) {
                #pragma unroll
                for (int dx = 0; dx < 3; ++dx) {
                    float w = wu.w[c * 9 + dy * 3 + dx];
                    s00 = fmaf(p[c][dy    ][dx    ], w, s00);
                    s01 = fmaf(p[c][dy    ][dx + 1], w, s01);
                    s10 = fmaf(p[c][dy + 1][dx    ], w, s10);
                    s11 = fmaf(p[c][dy + 1][dx + 1], w, s11);
                }
            }
        }
        float mx = fmaxf(fmaxf(s00, s01), fmaxf(s10, s11));
        pk.u[o] = f2bf(fmaxf(mx + sm_b[o], 0.f));
    }

    // mid NHWC bf16: [b][py][px][oc] — 128 B contiguous per thread
    uint4* mp = (uint4*)(mid + ((size_t)((b * HMID + py) * WMID + px)) * C1);
    #pragma unroll
    for (int g = 0; g < 8; ++g) mp[g] = pk.v[g];
}

// ---------------------------------------------------------------------------
// Kernel B: conv2 via bf16 MFMA implicit GEMM + bias + relu + 2x2 pool.
// Block: 512 thr (8 waves: 4 along x, 2 along oc). Conv tile 8y x 32x, 128 oc.
// LDS: halo 10 x 34 x 64ci bf16, [pos][ci] with XOR-swizzled 16B granules.
// Output: feat bf16 NHWC [b][y][x][oc] — lane-contiguous oc stores.
// ---------------------------------------------------------------------------
__global__ __launch_bounds__(512, 4)
void k_conv2_mfma(const ushort* __restrict__ mid, const ushort* __restrict__ Wt,
                  const float* __restrict__ b2, ushort* __restrict__ feat)
{
    __shared__ uint4 sm_in[340 * 8];   // 10*34 positions x 8 granules (16B = 8 ci)

    const int tid = threadIdx.x;
    const int tx = blockIdx.x;         // 0..7   (32 conv cols each)
    const int ty = blockIdx.y;         // 0..31  (8 conv rows each)
    const int b  = blockIdx.z;

    const int cy0 = ty * 8, cx0 = tx * 32;

    // ---- stage halo tile (global NHWC bf16 -> LDS, swizzled) ----
    for (int t = tid; t < 340 * 8; t += 512) {
        int pos = t >> 3, g = t & 7;
        int hy = pos / 34, hx = pos - hy * 34;
        int gy = cy0 - 1 + hy, gx = cx0 - 1 + hx;
        uint4 v = make_uint4(0, 0, 0, 0);
        if ((unsigned)gy < (unsigned)HMID && (unsigned)gx < (unsigned)WMID)
            v = *(const uint4*)(mid + (((size_t)(b * HMID + gy) * WMID + gx) * C1 + g * 8));
        sm_in[pos * 8 + (g ^ (pos & 7))] = v;
    }
    __syncthreads();

    // ---- wave / lane decomposition ----
    const int l   = tid & 63;
    const int wid = tid >> 6;
    const int wm  = wid & 3;        // x-offset wm*8
    const int wn  = wid >> 2;       // oc-offset wn*64
    const int c16 = l & 15;
    const int hi  = l >> 4;
    const int ylane = (c16 >> 1) & 1;
    const int xlane = ((c16 >> 2) << 1) | (c16 & 1);
    const int pos00 = ylane * 34 + wm * 8 + xlane;
    const ushort* wbp = Wt + ((size_t)(wn * 64 + c16) * 64 + 8 * hi);

    f32x4 acc[4][4] = {};

    for (int tap = 0; tap < 9; ++tap) {
        int dy = tap / 3, dx = tap - dy * 3;
        int po = pos00 + dy * 34 + dx;
        const ushort* wt = wbp + tap * 8192;
        #pragma unroll
        for (int k0 = 0; k0 < 2; ++k0) {
            short8 bf[4];
            #pragma unroll
            for (int fn = 0; fn < 4; ++fn)
                bf[fn] = *(const short8*)(wt + fn * 1024 + k0 * 32);
            #pragma unroll
            for (int fm = 0; fm < 4; ++fm) {
                int pos = po + fm * 68;
                int gi  = (hi + k0 * 4) ^ (pos & 7);
                short8 af = __builtin_bit_cast(short8, sm_in[pos * 8 + gi]);
                #pragma unroll
                for (int fn = 0; fn < 4; ++fn)
                    acc[fm][fn] = __builtin_amdgcn_mfma_f32_16x16x32_bf16(
                        af, bf[fn], acc[fm][fn], 0, 0, 0);
            }
        }
    }

    // ---- epilogue: pool 2x2 in-lane, store bf16 NHWC (oc contiguous) ----
    const int py0 = ty * 4;
    const int px  = tx * 16 + wm * 4 + hi;
    #pragma unroll
    for (int fn = 0; fn < 4; ++fn) {
        int oc = wn * 64 + fn * 16 + c16;
        float bb = b2[oc];
        #pragma unroll
        for (int fm = 0; fm < 4; ++fm) {
            f32x4 a4 = acc[fm][fn];
            float m = fmaxf(fmaxf(a4[0], a4[1]), fmaxf(a4[2], a4[3]));
            float v = fmaxf(m + bb, 0.f);
            feat[((size_t)(b * HFT + py0 + fm) * WFT + px) * C2 + oc] = f2bf(v);
        }
    }
}

// ---------------------------------------------------------------------------
// Kernel C: ROI crop + SPP from bf16 NHWC feat. Block per ROI.
// 256 threads: lane = channel pair (coalesced uint loads), tid>>6 = row-quarter.
// ---------------------------------------------------------------------------
__global__ __launch_bounds__(256)
void k_roi_spp(const ushort* __restrict__ feat, const int* __restrict__ rois,
               float* __restrict__ spp)
{
    __shared__ float sm_blk[128 * 17];

    const int tid = threadIdx.x;
    const int roi = blockIdx.x;

    const int bi = rois[roi * 5 + 0];
    int xm = (int)roundf((float)rois[roi * 5 + 1] * 0.25f);
    int ym = (int)roundf((float)rois[roi * 5 + 2] * 0.25f);
    xm = min(max(xm, 0), WFT - ROI_FT);
    ym = min(max(ym, 0), HFT - ROI_FT);

    const int cpair = (tid & 63) * 2;      // channels cpair, cpair+1
    const int by    = tid >> 6;            // 0..3 (8-row band)

    const ushort* base = feat + ((size_t)((bi * HFT + ym + by * 8)) * WFT + xm) * C2 + cpair;

    float mm[4][2];
    #pragma unroll
    for (int bx = 0; bx < 4; ++bx) { mm[bx][0] = -INFINITY; mm[bx][1] = -INFINITY; }

    for (int y = 0; y < 8; ++y) {
        const ushort* rowp = base + (size_t)y * (WFT * C2);
        #pragma unroll
        for (int bx = 0; bx < 4; ++bx) {
            #pragma unroll
            for (int j = 0; j < 8; ++j) {
                unsigned v = *(const unsigned*)(rowp + (bx * 8 + j) * C2);
                float f0 = __builtin_bit_cast(float, v << 16);
                float f1 = __builtin_bit_cast(float, v & 0xffff0000u);
                mm[bx][0] = fmaxf(mm[bx][0], f0);
                mm[bx][1] = fmaxf(mm[bx][1], f1);
            }
        }
    }
    #pragma unroll
    for (int bx = 0; bx < 4; ++bx) {
        sm_blk[cpair * 17 + by * 4 + bx]       = mm[bx][0];
        sm_blk[(cpair + 1) * 17 + by * 4 + bx] = mm[bx][1];
    }
    __syncthreads();

    if (tid < 128) {
        float v[16];
        #pragma unroll
        for (int k = 0; k < 16; ++k) v[k] = sm_blk[tid * 17 + k];
        float* o = spp + (size_t)roi * SPP_DIM;
        #pragma unroll
        for (int k = 0; k < 16; ++k) o[640 + tid * 16 + k] = v[k];
        float g = -INFINITY;
        #pragma unroll
        for (int qy = 0; qy < 2; ++qy) {
            #pragma unroll
            for (int qx = 0; qx < 2; ++qx) {
                float q = fmaxf(fmaxf(v[(2 * qy) * 4 + 2 * qx],     v[(2 * qy) * 4 + 2 * qx + 1]),
                                fmaxf(v[(2 * qy + 1) * 4 + 2 * qx], v[(2 * qy + 1) * 4 + 2 * qx + 1]));
                o[128 + tid * 4 + qy * 2 + qx] = q;
                g = fmaxf(g, q);
            }
        }
        o[tid] = g;
    }
}

// ---------------------------------------------------------------------------
// Kernel D: FC1 + relu. 16x16 output tile per block.
// ---------------------------------------------------------------------------
__global__ __launch_bounds__(256)
void k_fc1(const float* __restrict__ spp, const float* __restrict__ w,
           const float* __restrict__ bias, float* __restrict__ h)
{
    const int col = blockIdx.x * 16 + (threadIdx.x & 15);
    const int row = blockIdx.y * 16 + (threadIdx.x >> 4);
    const float* s = spp + (size_t)row * SPP_DIM;
    float acc = bias[col];
    for (int k = 0; k < SPP_DIM; k += 4) {
        float4 s4 = *(const float4*)(s + k);
        acc = fmaf(s4.x, w[(k + 0) * FC1_OUT + col], acc);
        acc = fmaf(s4.y, w[(k + 1) * FC1_OUT + col], acc);
        acc = fmaf(s4.z, w[(k + 2) * FC1_OUT + col], acc);
        acc = fmaf(s4.w, w[(k + 3) * FC1_OUT + col], acc);
    }
    h[row * FC1_OUT + col] = fmaxf(acc, 0.f);
}

// ---------------------------------------------------------------------------
// Kernel E: FC2. 16x16 output tile per block.
// ---------------------------------------------------------------------------
__global__ __launch_bounds__(256)
void k_fc2(const float* __restrict__ h, const float* __restrict__ w,
           const float* __restrict__ bias, float* __restrict__ out)
{
    const int col = blockIdx.x * 16 + (threadIdx.x & 15);
    const int row = blockIdx.y * 16 + (threadIdx.x >> 4);
    if (col >= NCLS) return;
    const float* hr = h + (size_t)row * FC1_OUT;
    float acc = bias[col];
    for (int k = 0; k < FC1_OUT; k += 4) {
        float4 h4 = *(const float4*)(hr + k);
        acc = fmaf(h4.x, w[(k + 0) * NCLS + col], acc);
        acc = fmaf(h4.y, w[(k + 1) * NCLS + col], acc);
        acc = fmaf(h4.z, w[(k + 2) * NCLS + col], acc);
        acc = fmaf(h4.w, w[(k + 3) * NCLS + col], acc);
    }
    out[row * NCLS + col] = acc;
}

// ---------------------------------------------------------------------------
extern "C" void kernel_launch(void* const* d_in, const int* in_sizes, int n_in,
                              void* d_out, int out_size, void* d_ws, size_t ws_size,
                              hipStream_t stream)
{
    const float* x     = (const float*)d_in[0];
    const int*   rois  = (const int*)  d_in[1];
    const float* w1    = (const float*)d_in[2];
    const float* b1    = (const float*)d_in[3];
    const float* w2    = (const float*)d_in[4];
    const float* b2    = (const float*)d_in[5];
    const float* fc1_w = (const float*)d_in[6];
    const float* fc1_b = (const float*)d_in[7];
    const float* fc2_w = (const float*)d_in[8];
    const float* fc2_b = (const float*)d_in[9];
    float* out = (float*)d_out;

    // workspace: mid bf16 NHWC | Wt bf16 | feat bf16 NHWC | spp f32 | h f32
    ushort* midb  = (ushort*)d_ws;
    ushort* Wt    = midb + (size_t)NB * HMID * WMID * C1;      // 33.55M elems
    ushort* featb = Wt + 9 * 128 * 64;                         // 73728 elems
    float*  spp   = (float*)(featb + (size_t)NB * HFT * WFT * C2);  // 16.78M
    float*  h     = spp + (size_t)NROIS * SPP_DIM;

    k_w2t       <<<dim3(288),       256, 0, stream>>>(w2, Wt);
    k_conv1_pool<<<dim3(256, NB),   256, 0, stream>>>(x, w1, b1, midb);
    k_conv2_mfma<<<dim3(8, 32, NB), 512, 0, stream>>>(midb, Wt, b2, featb);
    k_roi_spp   <<<dim3(NROIS),     256, 0, stream>>>(featb, rois, spp);
    k_fc1       <<<dim3(16, 16),    256, 0, stream>>>(spp, fc1_w, fc1_b, h);
    k_fc2       <<<dim3(63, 16),    256, 0, stream>>>(h, fc2_w, fc2_b, out);
}

// Round 4
// 316.352 us; speedup vs baseline: 5.1975x; 1.1917x over previous
//
#include <hip/hip_runtime.h>
#include <math.h>

// ---- problem constants ----
#define NB      8
#define C_IN    3
#define HIMG    512
#define WIMG    512
#define C1      64      // conv1 out channels
#define HMID    256     // after pool1
#define WMID    256
#define C2      128     // conv2 out channels (C_FEAT)
#define HFT     128     // after pool2
#define WFT     128
#define NROIS   256
#define ROI_FT  32
#define SPP_DIM 2688    // 128*(1+4+16)
#define FC1_OUT 256
#define NCLS    1000

typedef unsigned short ushort;
typedef __attribute__((ext_vector_type(8))) short short8;
typedef __attribute__((ext_vector_type(4))) float f32x4;

static __device__ __forceinline__ ushort f2bf(float f) {
    unsigned u = __builtin_bit_cast(unsigned, f);
    unsigned r = (u + 0x7fffu + ((u >> 16) & 1u)) >> 16;   // RNE
    return (ushort)r;
}

// ---------------------------------------------------------------------------
// Kernel W2: transpose w2 [oc][ci][3][3] fp32 -> Wt [tap][oc][ci] bf16
// ---------------------------------------------------------------------------
__global__ __launch_bounds__(256)
void k_w2t(const float* __restrict__ w2, ushort* __restrict__ Wt)
{
    int i = blockIdx.x * 256 + threadIdx.x;      // 9*128*64 = 73728
    if (i >= 9 * 128 * 64) return;
    int tap = i >> 13;
    int rem = i & 8191;
    int oc  = rem >> 6;
    int ci  = rem & 63;
    Wt[i] = f2bf(w2[(oc * 64 + ci) * 9 + tap]);
}

// ---------------------------------------------------------------------------
// Kernel W1: w1 [oc][ci][3][3] fp32 -> W1t [oc][k] bf16, k = tap*3+ci, pad 32
// ---------------------------------------------------------------------------
__global__ __launch_bounds__(256)
void k_w1t(const float* __restrict__ w1, ushort* __restrict__ W1t)
{
    int i = blockIdx.x * 256 + threadIdx.x;      // 64*32 = 2048
    if (i >= 2048) return;
    int oc = i >> 5, k = i & 31;
    float v = 0.f;
    if (k < 27) {
        int tap = k / 3, ci = k - 3 * tap;
        v = w1[oc * 27 + ci * 9 + tap];
    }
    W1t[i] = f2bf(v);
}

// ---------------------------------------------------------------------------
// Kernel A: conv1 via bf16 MFMA implicit GEMM + bias + relu + 2x2 pool.
// Block: 512 thr (8 waves: wm 0..3 x-offset, wn 0..1 oc-half). Tile 8y x 32x.
// K = 27 (3ci x 9taps) zero-padded to 32 — single MFMA chunk.
// A-frags gathered from bf16 LDS input tile (8 x ds_read_u16 per frag).
// Output mid bf16 NHWC via LDS-transpose + linear uint4 stores.
// ---------------------------------------------------------------------------
__global__ __launch_bounds__(512, 4)
void k_conv1_mfma(const float* __restrict__ x, const ushort* __restrict__ W1t,
                  const float* __restrict__ b1, ushort* __restrict__ mid)
{
    __shared__ ushort sm_x[3 * 10 * 36 + 8];     // input tile, row stride 36
    __shared__ ushort sm_o[4 * 16 * 64];         // pooled out [py][px][oc] 8KB

    const int tid = threadIdx.x;
    const int tx = blockIdx.x;    // 0..15 (32 conv cols)
    const int ty = blockIdx.y;    // 0..63 (8 conv rows)
    const int b  = blockIdx.z;

    const int cy0 = ty * 8, cx0 = tx * 32;

    // stage input halo 3 x 10 x 34 fp32 -> bf16
    for (int t = tid; t < 3 * 10 * 34; t += 512) {
        int ci  = t / 340;
        int rem = t - ci * 340;
        int r = rem / 34, c = rem - r * 34;
        int gy = cy0 - 1 + r, gx = cx0 - 1 + c;
        float v = 0.f;
        if ((unsigned)gy < (unsigned)HIMG && (unsigned)gx < (unsigned)WIMG)
            v = x[((b * C_IN + ci) * HIMG + gy) * WIMG + gx];
        sm_x[ci * 360 + r * 36 + c] = f2bf(v);
    }
    __syncthreads();

    const int l   = tid & 63;
    const int wid = tid >> 6;
    const int wm  = wid & 3;       // conv-x offset wm*8
    const int wn  = wid >> 2;      // oc offset wn*32
    const int c16 = l & 15;
    const int hi  = l >> 4;
    const int ylane = (c16 >> 1) & 1;
    const int xlane = ((c16 >> 2) << 1) | (c16 & 1);
    const int xloc  = wm * 8 + xlane;

    // per-j gather offsets: k = hi*8+j -> (tap, ci); k>=27 reads slot 0 (w=0)
    int offj[8];
    #pragma unroll
    for (int j = 0; j < 8; ++j) {
        int k = hi * 8 + j;
        int tap = k / 3, ci = k - 3 * tap;
        int dy = tap / 3, dx = tap - 3 * dy;
        offj[j] = (k < 27) ? (ci * 360 + dy * 36 + dx) : 0;
    }

    short8 bf[2];
    #pragma unroll
    for (int fn = 0; fn < 2; ++fn)
        bf[fn] = *(const short8*)(W1t + (wn * 32 + fn * 16 + c16) * 32 + hi * 8);

    f32x4 acc[4][2] = {};
    #pragma unroll
    for (int fm = 0; fm < 4; ++fm) {
        int base = (2 * fm + ylane) * 36 + xloc;
        union { ushort u[8]; short8 s; } av;
        #pragma unroll
        for (int j = 0; j < 8; ++j) av.u[j] = sm_x[offj[j] + base];
        #pragma unroll
        for (int fn = 0; fn < 2; ++fn)
            acc[fm][fn] = __builtin_amdgcn_mfma_f32_16x16x32_bf16(
                av.s, bf[fn], acc[fm][fn], 0, 0, 0);
    }

    // epilogue: pool 2x2 (lane's 4 C/D regs), stage to LDS, linear store
    const int pxl = wm * 4 + hi;   // pooled px local 0..15
    #pragma unroll
    for (int fn = 0; fn < 2; ++fn) {
        int oc = wn * 32 + fn * 16 + c16;
        float bb = b1[oc];
        #pragma unroll
        for (int fm = 0; fm < 4; ++fm) {
            f32x4 a4 = acc[fm][fn];
            float m = fmaxf(fmaxf(a4[0], a4[1]), fmaxf(a4[2], a4[3]));
            sm_o[(fm * 16 + pxl) * 64 + oc] = f2bf(fmaxf(m + bb, 0.f));
        }
    }
    __syncthreads();
    {
        int row = tid >> 7;        // 0..3 local pooled row
        int off = tid & 127;       // 128 x 16B = 2KB per row
        uint4 v = *(const uint4*)(sm_o + row * (16 * 64) + off * 8);
        int py = ty * 4 + row;
        uint4* dst = (uint4*)(mid + ((size_t)(b * HMID + py) * WMID + tx * 16) * C1) + off;
        *dst = v;
    }
}

// ---------------------------------------------------------------------------
// Kernel B: conv2 via bf16 MFMA implicit GEMM + bias + relu + 2x2 pool.
// Block: 512 thr (8 waves: 4 along x, 2 along oc). Conv tile 8y x 32x, 128 oc.
// LDS: halo 10 x 34 x 64ci bf16, [pos][ci] with XOR-swizzled 16B granules.
// Output: feat bf16 NHWC via LDS-transpose + linear uint4 stores (full lines).
// ---------------------------------------------------------------------------
__global__ __launch_bounds__(512, 4)
void k_conv2_mfma(const ushort* __restrict__ mid, const ushort* __restrict__ Wt,
                  const float* __restrict__ b2, ushort* __restrict__ feat)
{
    __shared__ uint4 sm_in[340 * 8];   // 10*34 positions x 8 granules (16B = 8 ci)

    const int tid = threadIdx.x;
    const int tx = blockIdx.x;         // 0..7   (32 conv cols each)
    const int ty = blockIdx.y;         // 0..31  (8 conv rows each)
    const int b  = blockIdx.z;

    const int cy0 = ty * 8, cx0 = tx * 32;

    // ---- stage halo tile (global NHWC bf16 -> LDS, swizzled) ----
    for (int t = tid; t < 340 * 8; t += 512) {
        int pos = t >> 3, g = t & 7;
        int hy = pos / 34, hx = pos - hy * 34;
        int gy = cy0 - 1 + hy, gx = cx0 - 1 + hx;
        uint4 v = make_uint4(0, 0, 0, 0);
        if ((unsigned)gy < (unsigned)HMID && (unsigned)gx < (unsigned)WMID)
            v = *(const uint4*)(mid + (((size_t)(b * HMID + gy) * WMID + gx) * C1 + g * 8));
        sm_in[pos * 8 + (g ^ (pos & 7))] = v;
    }
    __syncthreads();

    // ---- wave / lane decomposition ----
    const int l   = tid & 63;
    const int wid = tid >> 6;
    const int wm  = wid & 3;        // x-offset wm*8
    const int wn  = wid >> 2;       // oc-offset wn*64
    const int c16 = l & 15;
    const int hi  = l >> 4;
    const int ylane = (c16 >> 1) & 1;
    const int xlane = ((c16 >> 2) << 1) | (c16 & 1);
    const int pos00 = ylane * 34 + wm * 8 + xlane;
    const ushort* wbp = Wt + ((size_t)(wn * 64 + c16) * 64 + 8 * hi);

    f32x4 acc[4][4] = {};

    for (int tap = 0; tap < 9; ++tap) {
        int dy = tap / 3, dx = tap - dy * 3;
        int po = pos00 + dy * 34 + dx;
        const ushort* wt = wbp + tap * 8192;
        #pragma unroll
        for (int k0 = 0; k0 < 2; ++k0) {
            short8 bfr[4];
            #pragma unroll
            for (int fn = 0; fn < 4; ++fn)
                bfr[fn] = *(const short8*)(wt + fn * 1024 + k0 * 32);
            #pragma unroll
            for (int fm = 0; fm < 4; ++fm) {
                int pos = po + fm * 68;
                int gi  = (hi + k0 * 4) ^ (pos & 7);
                short8 af = __builtin_bit_cast(short8, sm_in[pos * 8 + gi]);
                #pragma unroll
                for (int fn = 0; fn < 4; ++fn)
                    acc[fm][fn] = __builtin_amdgcn_mfma_f32_16x16x32_bf16(
                        af, bfr[fn], acc[fm][fn], 0, 0, 0);
            }
        }
    }

    // ---- epilogue: pool 2x2 in-lane -> LDS [py][px][oc] -> linear stores ----
    __syncthreads();                       // all waves done reading sm_in
    ushort* sm_o = (ushort*)sm_in;         // reuse: 4*16*128*2B = 16KB
    const int pxl = wm * 4 + hi;
    #pragma unroll
    for (int fn = 0; fn < 4; ++fn) {
        int oc = wn * 64 + fn * 16 + c16;
        float bb = b2[oc];
        #pragma unroll
        for (int fm = 0; fm < 4; ++fm) {
            f32x4 a4 = acc[fm][fn];
            float m = fmaxf(fmaxf(a4[0], a4[1]), fmaxf(a4[2], a4[3]));
            sm_o[(fm * 16 + pxl) * 128 + oc] = f2bf(fmaxf(m + bb, 0.f));
        }
    }
    __syncthreads();
    const int py0 = ty * 4;
    #pragma unroll
    for (int pass = 0; pass < 2; ++pass) {
        int idx = pass * 512 + tid;        // 0..1023
        int row = idx >> 8;                // 0..3
        int off = idx & 255;               // 256 x 16B = 4KB per row
        uint4 v = *(const uint4*)(sm_o + row * (16 * 128) + off * 8);
        uint4* dst = (uint4*)(feat + ((size_t)(b * HFT + py0 + row) * WFT + tx * 16) * C2) + off;
        *dst = v;
    }
}

// ---------------------------------------------------------------------------
// Kernel C: ROI crop + SPP from bf16 NHWC feat. Block per ROI.
// ---------------------------------------------------------------------------
__global__ __launch_bounds__(256)
void k_roi_spp(const ushort* __restrict__ feat, const int* __restrict__ rois,
               float* __restrict__ spp)
{
    __shared__ float sm_blk[128 * 17];

    const int tid = threadIdx.x;
    const int roi = blockIdx.x;

    const int bi = rois[roi * 5 + 0];
    int xm = (int)roundf((float)rois[roi * 5 + 1] * 0.25f);
    int ym = (int)roundf((float)rois[roi * 5 + 2] * 0.25f);
    xm = min(max(xm, 0), WFT - ROI_FT);
    ym = min(max(ym, 0), HFT - ROI_FT);

    const int cpair = (tid & 63) * 2;
    const int by    = tid >> 6;

    const ushort* base = feat + ((size_t)((bi * HFT + ym + by * 8)) * WFT + xm) * C2 + cpair;

    float mm[4][2];
    #pragma unroll
    for (int bx = 0; bx < 4; ++bx) { mm[bx][0] = -INFINITY; mm[bx][1] = -INFINITY; }

    for (int y = 0; y < 8; ++y) {
        const ushort* rowp = base + (size_t)y * (WFT * C2);
        #pragma unroll
        for (int bx = 0; bx < 4; ++bx) {
            #pragma unroll
            for (int j = 0; j < 8; ++j) {
                unsigned v = *(const unsigned*)(rowp + (bx * 8 + j) * C2);
                float f0 = __builtin_bit_cast(float, v << 16);
                float f1 = __builtin_bit_cast(float, v & 0xffff0000u);
                mm[bx][0] = fmaxf(mm[bx][0], f0);
                mm[bx][1] = fmaxf(mm[bx][1], f1);
            }
        }
    }
    #pragma unroll
    for (int bx = 0; bx < 4; ++bx) {
        sm_blk[cpair * 17 + by * 4 + bx]       = mm[bx][0];
        sm_blk[(cpair + 1) * 17 + by * 4 + bx] = mm[bx][1];
    }
    __syncthreads();

    if (tid < 128) {
        float v[16];
        #pragma unroll
        for (int k = 0; k < 16; ++k) v[k] = sm_blk[tid * 17 + k];
        float* o = spp + (size_t)roi * SPP_DIM;
        #pragma unroll
        for (int k = 0; k < 16; ++k) o[640 + tid * 16 + k] = v[k];
        float g = -INFINITY;
        #pragma unroll
        for (int qy = 0; qy < 2; ++qy) {
            #pragma unroll
            for (int qx = 0; qx < 2; ++qx) {
                float q = fmaxf(fmaxf(v[(2 * qy) * 4 + 2 * qx],     v[(2 * qy) * 4 + 2 * qx + 1]),
                                fmaxf(v[(2 * qy + 1) * 4 + 2 * qx], v[(2 * qy + 1) * 4 + 2 * qx + 1]));
                o[128 + tid * 4 + qy * 2 + qx] = q;
                g = fmaxf(g, q);
            }
        }
        o[tid] = g;
    }
}

// ---------------------------------------------------------------------------
// Kernel D: FC1 + relu. 16x16 output tile per block.
// ---------------------------------------------------------------------------
__global__ __launch_bounds__(256)
void k_fc1(const float* __restrict__ spp, const float* __restrict__ w,
           const float* __restrict__ bias, float* __restrict__ h)
{
    const int col = blockIdx.x * 16 + (threadIdx.x & 15);
    const int row = blockIdx.y * 16 + (threadIdx.x >> 4);
    const float* s = spp + (size_t)row * SPP_DIM;
    float acc = bias[col];
    for (int k = 0; k < SPP_DIM; k += 4) {
        float4 s4 = *(const float4*)(s + k);
        acc = fmaf(s4.x, w[(k + 0) * FC1_OUT + col], acc);
        acc = fmaf(s4.y, w[(k + 1) * FC1_OUT + col], acc);
        acc = fmaf(s4.z, w[(k + 2) * FC1_OUT + col], acc);
        acc = fmaf(s4.w, w[(k + 3) * FC1_OUT + col], acc);
    }
    h[row * FC1_OUT + col] = fmaxf(acc, 0.f);
}

// ---------------------------------------------------------------------------
// Kernel E: FC2. 16x16 output tile per block.
// ---------------------------------------------------------------------------
__global__ __launch_bounds__(256)
void k_fc2(const float* __restrict__ h, const float* __restrict__ w,
           const float* __restrict__ bias, float* __restrict__ out)
{
    const int col = blockIdx.x * 16 + (threadIdx.x & 15);
    const int row = blockIdx.y * 16 + (threadIdx.x >> 4);
    if (col >= NCLS) return;
    const float* hr = h + (size_t)row * FC1_OUT;
    float acc = bias[col];
    for (int k = 0; k < FC1_OUT; k += 4) {
        float4 h4 = *(const float4*)(hr + k);
        acc = fmaf(h4.x, w[(k + 0) * NCLS + col], acc);
        acc = fmaf(h4.y, w[(k + 1) * NCLS + col], acc);
        acc = fmaf(h4.z, w[(k + 2) * NCLS + col], acc);
        acc = fmaf(h4.w, w[(k + 3) * NCLS + col], acc);
    }
    out[row * NCLS + col] = acc;
}

// ---------------------------------------------------------------------------
extern "C" void kernel_launch(void* const* d_in, const int* in_sizes, int n_in,
                              void* d_out, int out_size, void* d_ws, size_t ws_size,
                              hipStream_t stream)
{
    const float* x     = (const float*)d_in[0];
    const int*   rois  = (const int*)  d_in[1];
    const float* w1    = (const float*)d_in[2];
    const float* b1    = (const float*)d_in[3];
    const float* w2    = (const float*)d_in[4];
    const float* b2    = (const float*)d_in[5];
    const float* fc1_w = (const float*)d_in[6];
    const float* fc1_b = (const float*)d_in[7];
    const float* fc2_w = (const float*)d_in[8];
    const float* fc2_b = (const float*)d_in[9];
    float* out = (float*)d_out;

    // workspace: mid bf16 | Wt bf16 | W1t bf16 | feat bf16 | spp f32 | h f32
    ushort* midb  = (ushort*)d_ws;
    ushort* Wt    = midb + (size_t)NB * HMID * WMID * C1;           // 33.55M
    ushort* W1t   = Wt + 9 * 128 * 64;                              // 73728
    ushort* featb = W1t + 2048;
    float*  spp   = (float*)(featb + (size_t)NB * HFT * WFT * C2);  // 16.78M
    float*  h     = spp + (size_t)NROIS * SPP_DIM;

    k_w2t       <<<dim3(288),       256, 0, stream>>>(w2, Wt);
    k_w1t       <<<dim3(8),         256, 0, stream>>>(w1, W1t);
    k_conv1_mfma<<<dim3(16, 64, NB), 512, 0, stream>>>(x, W1t, b1, midb);
    k_conv2_mfma<<<dim3(8, 32, NB), 512, 0, stream>>>(midb, Wt, b2, featb);
    k_roi_spp   <<<dim3(NROIS),     256, 0, stream>>>(featb, rois, spp);
    k_fc1       <<<dim3(16, 16),    256, 0, stream>>>(spp, fc1_w, fc1_b, h);
    k_fc2       <<<dim3(63, 16),    256, 0, stream>>>(h, fc2_w, fc2_b, out);
}

// Round 5
// 305.341 us; speedup vs baseline: 5.3850x; 1.0361x over previous
//
#include <hip/hip_runtime.h>
#include <math.h>

// ---- problem constants ----
#define NB      8
#define C_IN    3
#define HIMG    512
#define WIMG    512
#define C1      64      // conv1 out channels
#define HMID    256     // after pool1
#define WMID    256
#define C2      128     // conv2 out channels (C_FEAT)
#define HFT     128     // after pool2
#define WFT     128
#define NROIS   256
#define ROI_FT  32
#define SPP_DIM 2688    // 128*(1+4+16)
#define FC1_OUT 256
#define NCLS    1000

typedef unsigned short ushort;
typedef __attribute__((ext_vector_type(8))) short short8;
typedef __attribute__((ext_vector_type(4))) float f32x4;

static __device__ __forceinline__ ushort f2bf(float f) {
    unsigned u = __builtin_bit_cast(unsigned, f);
    unsigned r = (u + 0x7fffu + ((u >> 16) & 1u)) >> 16;   // RNE
    return (ushort)r;
}

// ---------------------------------------------------------------------------
// Kernel W2: transpose w2 [oc][ci][3][3] fp32 -> Wt [tap][oc][ci] bf16
// ---------------------------------------------------------------------------
__global__ __launch_bounds__(256)
void k_w2t(const float* __restrict__ w2, ushort* __restrict__ Wt)
{
    int i = blockIdx.x * 256 + threadIdx.x;      // 9*128*64 = 73728
    if (i >= 9 * 128 * 64) return;
    int tap = i >> 13;
    int rem = i & 8191;
    int oc  = rem >> 6;
    int ci  = rem & 63;
    Wt[i] = f2bf(w2[(oc * 64 + ci) * 9 + tap]);
}

// ---------------------------------------------------------------------------
// Kernel W1: w1 [oc][ci][3][3] fp32 -> W1t [oc][k] bf16, k = tap*3+ci, pad 32
// ---------------------------------------------------------------------------
__global__ __launch_bounds__(256)
void k_w1t(const float* __restrict__ w1, ushort* __restrict__ W1t)
{
    int i = blockIdx.x * 256 + threadIdx.x;      // 64*32 = 2048
    if (i >= 2048) return;
    int oc = i >> 5, k = i & 31;
    float v = 0.f;
    if (k < 27) {
        int tap = k / 3, ci = k - 3 * tap;
        v = w1[oc * 27 + ci * 9 + tap];
    }
    W1t[i] = f2bf(v);
}

// ---------------------------------------------------------------------------
// Kernel A: conv1 via bf16 MFMA implicit GEMM + bias + relu + 2x2 pool.
// Block: 512 thr (8 waves: wm 0..3 x-offset, wn 0..1 oc-half). Tile 8y x 32x.
// K = 27 (3ci x 9taps) zero-padded to 32 — single MFMA chunk.
// ---------------------------------------------------------------------------
__global__ __launch_bounds__(512, 4)
void k_conv1_mfma(const float* __restrict__ x, const ushort* __restrict__ W1t,
                  const float* __restrict__ b1, ushort* __restrict__ mid)
{
    __shared__ ushort sm_x[3 * 10 * 36 + 8];     // input tile, row stride 36
    __shared__ ushort sm_o[4 * 16 * 64];         // pooled out [py][px][oc] 8KB

    const int tid = threadIdx.x;
    const int tx = blockIdx.x;    // 0..15 (32 conv cols)
    const int ty = blockIdx.y;    // 0..63 (8 conv rows)
    const int b  = blockIdx.z;

    const int cy0 = ty * 8, cx0 = tx * 32;

    // stage input halo 3 x 10 x 34 fp32 -> bf16
    for (int t = tid; t < 3 * 10 * 34; t += 512) {
        int ci  = t / 340;
        int rem = t - ci * 340;
        int r = rem / 34, c = rem - r * 34;
        int gy = cy0 - 1 + r, gx = cx0 - 1 + c;
        float v = 0.f;
        if ((unsigned)gy < (unsigned)HIMG && (unsigned)gx < (unsigned)WIMG)
            v = x[((b * C_IN + ci) * HIMG + gy) * WIMG + gx];
        sm_x[ci * 360 + r * 36 + c] = f2bf(v);
    }
    __syncthreads();

    const int l   = tid & 63;
    const int wid = tid >> 6;
    const int wm  = wid & 3;       // conv-x offset wm*8
    const int wn  = wid >> 2;      // oc offset wn*32
    const int c16 = l & 15;
    const int hi  = l >> 4;
    const int ylane = (c16 >> 1) & 1;
    const int xlane = ((c16 >> 2) << 1) | (c16 & 1);
    const int xloc  = wm * 8 + xlane;

    // per-j gather offsets: k = hi*8+j -> (tap, ci); k>=27 reads slot 0 (w=0)
    int offj[8];
    #pragma unroll
    for (int j = 0; j < 8; ++j) {
        int k = hi * 8 + j;
        int tap = k / 3, ci = k - 3 * tap;
        int dy = tap / 3, dx = tap - 3 * dy;
        offj[j] = (k < 27) ? (ci * 360 + dy * 36 + dx) : 0;
    }

    short8 bf[2];
    #pragma unroll
    for (int fn = 0; fn < 2; ++fn)
        bf[fn] = *(const short8*)(W1t + (wn * 32 + fn * 16 + c16) * 32 + hi * 8);

    f32x4 acc[4][2] = {};
    #pragma unroll
    for (int fm = 0; fm < 4; ++fm) {
        int base = (2 * fm + ylane) * 36 + xloc;
        union { ushort u[8]; short8 s; } av;
        #pragma unroll
        for (int j = 0; j < 8; ++j) av.u[j] = sm_x[offj[j] + base];
        #pragma unroll
        for (int fn = 0; fn < 2; ++fn)
            acc[fm][fn] = __builtin_amdgcn_mfma_f32_16x16x32_bf16(
                av.s, bf[fn], acc[fm][fn], 0, 0, 0);
    }

    // epilogue: pool 2x2 (lane's 4 C/D regs), stage to LDS, linear store
    const int pxl = wm * 4 + hi;   // pooled px local 0..15
    #pragma unroll
    for (int fn = 0; fn < 2; ++fn) {
        int oc = wn * 32 + fn * 16 + c16;
        float bb = b1[oc];
        #pragma unroll
        for (int fm = 0; fm < 4; ++fm) {
            f32x4 a4 = acc[fm][fn];
            float m = fmaxf(fmaxf(a4[0], a4[1]), fmaxf(a4[2], a4[3]));
            sm_o[(fm * 16 + pxl) * 64 + oc] = f2bf(fmaxf(m + bb, 0.f));
        }
    }
    __syncthreads();
    {
        int row = tid >> 7;        // 0..3 local pooled row
        int off = tid & 127;       // 128 x 16B = 2KB per row
        uint4 v = *(const uint4*)(sm_o + row * (16 * 64) + off * 8);
        int py = ty * 4 + row;
        uint4* dst = (uint4*)(mid + ((size_t)(b * HMID + py) * WMID + tx * 16) * C1) + off;
        *dst = v;
    }
}

// ---------------------------------------------------------------------------
// Kernel B: conv2 via bf16 MFMA implicit GEMM + bias + relu + 2x2 pool.
// Block: 512 thr (8 waves: 4 along x, 2 along oc). Conv tile 8y x 32x, 128 oc.
// LDS: halo 10 x 34 x 64ci bf16, [pos][ci] with XOR-swizzled 16B granules.
// __launch_bounds__(512, 2): cap 256 unified VGPRs — acc[4][4] (64 AGPR) +
// working set must NOT spill (R2-R4 showed ~190 MB/dispatch scratch traffic
// at the (512,4) 128-reg cap).
// ---------------------------------------------------------------------------
__global__ __launch_bounds__(512, 2)
void k_conv2_mfma(const ushort* __restrict__ mid, const ushort* __restrict__ Wt,
                  const float* __restrict__ b2, ushort* __restrict__ feat)
{
    __shared__ uint4 sm_in[340 * 8];   // 10*34 positions x 8 granules (16B = 8 ci)

    const int tid = threadIdx.x;
    const int tx = blockIdx.x;         // 0..7   (32 conv cols each)
    const int ty = blockIdx.y;         // 0..31  (8 conv rows each)
    const int b  = blockIdx.z;

    const int cy0 = ty * 8, cx0 = tx * 32;

    // ---- stage halo tile (global NHWC bf16 -> LDS, swizzled) ----
    for (int t = tid; t < 340 * 8; t += 512) {
        int pos = t >> 3, g = t & 7;
        int hy = pos / 34, hx = pos - hy * 34;
        int gy = cy0 - 1 + hy, gx = cx0 - 1 + hx;
        uint4 v = make_uint4(0, 0, 0, 0);
        if ((unsigned)gy < (unsigned)HMID && (unsigned)gx < (unsigned)WMID)
            v = *(const uint4*)(mid + (((size_t)(b * HMID + gy) * WMID + gx) * C1 + g * 8));
        sm_in[pos * 8 + (g ^ (pos & 7))] = v;
    }
    __syncthreads();

    // ---- wave / lane decomposition ----
    const int l   = tid & 63;
    const int wid = tid >> 6;
    const int wm  = wid & 3;        // x-offset wm*8
    const int wn  = wid >> 2;       // oc-offset wn*64
    const int c16 = l & 15;
    const int hi  = l >> 4;
    const int ylane = (c16 >> 1) & 1;
    const int xlane = ((c16 >> 2) << 1) | (c16 & 1);
    const int pos00 = ylane * 34 + wm * 8 + xlane;
    const ushort* wbp = Wt + ((size_t)(wn * 64 + c16) * 64 + 8 * hi);

    f32x4 acc[4][4] = {};

    for (int tap = 0; tap < 9; ++tap) {
        int dy = tap / 3, dx = tap - dy * 3;
        int po = pos00 + dy * 34 + dx;
        const ushort* wt = wbp + tap * 8192;
        #pragma unroll
        for (int k0 = 0; k0 < 2; ++k0) {
            short8 bfr[4];
            #pragma unroll
            for (int fn = 0; fn < 4; ++fn)
                bfr[fn] = *(const short8*)(wt + fn * 1024 + k0 * 32);
            #pragma unroll
            for (int fm = 0; fm < 4; ++fm) {
                int pos = po + fm * 68;
                int gi  = (hi + k0 * 4) ^ (pos & 7);
                short8 af = __builtin_bit_cast(short8, sm_in[pos * 8 + gi]);
                #pragma unroll
                for (int fn = 0; fn < 4; ++fn)
                    acc[fm][fn] = __builtin_amdgcn_mfma_f32_16x16x32_bf16(
                        af, bfr[fn], acc[fm][fn], 0, 0, 0);
            }
        }
    }

    // ---- epilogue: pool 2x2 in-lane -> LDS [py][px][oc] -> linear stores ----
    __syncthreads();                       // all waves done reading sm_in
    ushort* sm_o = (ushort*)sm_in;         // reuse: 4*16*128*2B = 16KB
    const int pxl = wm * 4 + hi;
    #pragma unroll
    for (int fn = 0; fn < 4; ++fn) {
        int oc = wn * 64 + fn * 16 + c16;
        float bb = b2[oc];
        #pragma unroll
        for (int fm = 0; fm < 4; ++fm) {
            f32x4 a4 = acc[fm][fn];
            float m = fmaxf(fmaxf(a4[0], a4[1]), fmaxf(a4[2], a4[3]));
            sm_o[(fm * 16 + pxl) * 128 + oc] = f2bf(fmaxf(m + bb, 0.f));
        }
    }
    __syncthreads();
    const int py0 = ty * 4;
    #pragma unroll
    for (int pass = 0; pass < 2; ++pass) {
        int idx = pass * 512 + tid;        // 0..1023
        int row = idx >> 8;                // 0..3
        int off = idx & 255;               // 256 x 16B = 4KB per row
        uint4 v = *(const uint4*)(sm_o + row * (16 * 128) + off * 8);
        uint4* dst = (uint4*)(feat + ((size_t)(b * HFT + py0 + row) * WFT + tx * 16) * C2) + off;
        *dst = v;
    }
}

// ---------------------------------------------------------------------------
// Kernel C: ROI crop + SPP from bf16 NHWC feat. Block per ROI.
// ---------------------------------------------------------------------------
__global__ __launch_bounds__(256)
void k_roi_spp(const ushort* __restrict__ feat, const int* __restrict__ rois,
               float* __restrict__ spp)
{
    __shared__ float sm_blk[128 * 17];

    const int tid = threadIdx.x;
    const int roi = blockIdx.x;

    const int bi = rois[roi * 5 + 0];
    int xm = (int)roundf((float)rois[roi * 5 + 1] * 0.25f);
    int ym = (int)roundf((float)rois[roi * 5 + 2] * 0.25f);
    xm = min(max(xm, 0), WFT - ROI_FT);
    ym = min(max(ym, 0), HFT - ROI_FT);

    const int cpair = (tid & 63) * 2;
    const int by    = tid >> 6;

    const ushort* base = feat + ((size_t)((bi * HFT + ym + by * 8)) * WFT + xm) * C2 + cpair;

    float mm[4][2];
    #pragma unroll
    for (int bx = 0; bx < 4; ++bx) { mm[bx][0] = -INFINITY; mm[bx][1] = -INFINITY; }

    for (int y = 0; y < 8; ++y) {
        const ushort* rowp = base + (size_t)y * (WFT * C2);
        #pragma unroll
        for (int bx = 0; bx < 4; ++bx) {
            #pragma unroll
            for (int j = 0; j < 8; ++j) {
                unsigned v = *(const unsigned*)(rowp + (bx * 8 + j) * C2);
                float f0 = __builtin_bit_cast(float, v << 16);
                float f1 = __builtin_bit_cast(float, v & 0xffff0000u);
                mm[bx][0] = fmaxf(mm[bx][0], f0);
                mm[bx][1] = fmaxf(mm[bx][1], f1);
            }
        }
    }
    #pragma unroll
    for (int bx = 0; bx < 4; ++bx) {
        sm_blk[cpair * 17 + by * 4 + bx]       = mm[bx][0];
        sm_blk[(cpair + 1) * 17 + by * 4 + bx] = mm[bx][1];
    }
    __syncthreads();

    if (tid < 128) {
        float v[16];
        #pragma unroll
        for (int k = 0; k < 16; ++k) v[k] = sm_blk[tid * 17 + k];
        float* o = spp + (size_t)roi * SPP_DIM;
        #pragma unroll
        for (int k = 0; k < 16; ++k) o[640 + tid * 16 + k] = v[k];
        float g = -INFINITY;
        #pragma unroll
        for (int qy = 0; qy < 2; ++qy) {
            #pragma unroll
            for (int qx = 0; qx < 2; ++qx) {
                float q = fmaxf(fmaxf(v[(2 * qy) * 4 + 2 * qx],     v[(2 * qy) * 4 + 2 * qx + 1]),
                                fmaxf(v[(2 * qy + 1) * 4 + 2 * qx], v[(2 * qy + 1) * 4 + 2 * qx + 1]));
                o[128 + tid * 4 + qy * 2 + qx] = q;
                g = fmaxf(g, q);
            }
        }
        o[tid] = g;
    }
}

// ---------------------------------------------------------------------------
// Kernel D: FC1 + relu. 16x16 output tile per block.
// ---------------------------------------------------------------------------
__global__ __launch_bounds__(256)
void k_fc1(const float* __restrict__ spp, const float* __restrict__ w,
           const float* __restrict__ bias, float* __restrict__ h)
{
    const int col = blockIdx.x * 16 + (threadIdx.x & 15);
    const int row = blockIdx.y * 16 + (threadIdx.x >> 4);
    const float* s = spp + (size_t)row * SPP_DIM;
    float acc = bias[col];
    for (int k = 0; k < SPP_DIM; k += 4) {
        float4 s4 = *(const float4*)(s + k);
        acc = fmaf(s4.x, w[(k + 0) * FC1_OUT + col], acc);
        acc = fmaf(s4.y, w[(k + 1) * FC1_OUT + col], acc);
        acc = fmaf(s4.z, w[(k + 2) * FC1_OUT + col], acc);
        acc = fmaf(s4.w, w[(k + 3) * FC1_OUT + col], acc);
    }
    h[row * FC1_OUT + col] = fmaxf(acc, 0.f);
}

// ---------------------------------------------------------------------------
// Kernel E: FC2. 16x16 output tile per block.
// ---------------------------------------------------------------------------
__global__ __launch_bounds__(256)
void k_fc2(const float* __restrict__ h, const float* __restrict__ w,
           const float* __restrict__ bias, float* __restrict__ out)
{
    const int col = blockIdx.x * 16 + (threadIdx.x & 15);
    const int row = blockIdx.y * 16 + (threadIdx.x >> 4);
    if (col >= NCLS) return;
    const float* hr = h + (size_t)row * FC1_OUT;
    float acc = bias[col];
    for (int k = 0; k < FC1_OUT; k += 4) {
        float4 h4 = *(const float4*)(hr + k);
        acc = fmaf(h4.x, w[(k + 0) * NCLS + col], acc);
        acc = fmaf(h4.y, w[(k + 1) * NCLS + col], acc);
        acc = fmaf(h4.z, w[(k + 2) * NCLS + col], acc);
        acc = fmaf(h4.w, w[(k + 3) * NCLS + col], acc);
    }
    out[row * NCLS + col] = acc;
}

// ---------------------------------------------------------------------------
extern "C" void kernel_launch(void* const* d_in, const int* in_sizes, int n_in,
                              void* d_out, int out_size, void* d_ws, size_t ws_size,
                              hipStream_t stream)
{
    const float* x     = (const float*)d_in[0];
    const int*   rois  = (const int*)  d_in[1];
    const float* w1    = (const float*)d_in[2];
    const float* b1    = (const float*)d_in[3];
    const float* w2    = (const float*)d_in[4];
    const float* b2    = (const float*)d_in[5];
    const float* fc1_w = (const float*)d_in[6];
    const float* fc1_b = (const float*)d_in[7];
    const float* fc2_w = (const float*)d_in[8];
    const float* fc2_b = (const float*)d_in[9];
    float* out = (float*)d_out;

    // workspace: mid bf16 | Wt bf16 | W1t bf16 | feat bf16 | spp f32 | h f32
    ushort* midb  = (ushort*)d_ws;
    ushort* Wt    = midb + (size_t)NB * HMID * WMID * C1;           // 33.55M
    ushort* W1t   = Wt + 9 * 128 * 64;                              // 73728
    ushort* featb = W1t + 2048;
    float*  spp   = (float*)(featb + (size_t)NB * HFT * WFT * C2);  // 16.78M
    float*  h     = spp + (size_t)NROIS * SPP_DIM;

    k_w2t       <<<dim3(288),       256, 0, stream>>>(w2, Wt);
    k_w1t       <<<dim3(8),         256, 0, stream>>>(w1, W1t);
    k_conv1_mfma<<<dim3(16, 64, NB), 512, 0, stream>>>(x, W1t, b1, midb);
    k_conv2_mfma<<<dim3(8, 32, NB), 512, 0, stream>>>(midb, Wt, b2, featb);
    k_roi_spp   <<<dim3(NROIS),     256, 0, stream>>>(featb, rois, spp);
    k_fc1       <<<dim3(16, 16),    256, 0, stream>>>(spp, fc1_w, fc1_b, h);
    k_fc2       <<<dim3(63, 16),    256, 0, stream>>>(h, fc2_w, fc2_b, out);
}